// Round 1
// baseline (434.843 us; speedup 1.0000x reference)
//
#include <hip/hip_runtime.h>

#define HW 262144           // 512*512
#define CIN 16
#define OUTC 16

// ws layout (in floats)
#define WS_PARTIALS 0       // [2048][6]
#define WS_COS      12288   // [8]
#define WS_W2D      12304   // [8][16][9][16] = 18432

// ---------------------------------------------------------------------------
// Kernel 1: streaming reduction over x.
// z_c = sum_k rot_w[c,k]*x[b,k,p] + rot_b[c]  (c = 0..2)
// per block (fixed batch b): partial sums of z_c and z_c^2.
// ---------------------------------------------------------------------------
__global__ __launch_bounds__(256) void k_reduce(const float* __restrict__ x,
                                                const float* __restrict__ rot_w,
                                                const float* __restrict__ rot_b,
                                                float* __restrict__ partials) {
  const int blk = blockIdx.x;       // 0..2047
  const int b = blk >> 8;           // batch
  const int s = blk & 255;          // strip within batch
  const int t = threadIdx.x;

  float rw[3][16];
#pragma unroll
  for (int k = 0; k < 3; k++)
#pragma unroll
    for (int c = 0; c < 16; c++) rw[k][c] = rot_w[k * 16 + c];
  float rb[3];
#pragma unroll
  for (int k = 0; k < 3; k++) rb[k] = rot_b[k];

  const float* xb = x + (size_t)b * CIN * HW + s * 1024 + t * 4;

  float z[3][4];
#pragma unroll
  for (int k = 0; k < 3; k++)
#pragma unroll
    for (int j = 0; j < 4; j++) z[k][j] = 0.f;

#pragma unroll
  for (int c = 0; c < 16; c++) {
    float4 v = *reinterpret_cast<const float4*>(xb + (size_t)c * HW);
#pragma unroll
    for (int k = 0; k < 3; k++) {
      z[k][0] += rw[k][c] * v.x;
      z[k][1] += rw[k][c] * v.y;
      z[k][2] += rw[k][c] * v.z;
      z[k][3] += rw[k][c] * v.w;
    }
  }

  float vals[6];
#pragma unroll
  for (int k = 0; k < 3; k++) {
    float sz = 0.f, sz2 = 0.f;
#pragma unroll
    for (int j = 0; j < 4; j++) {
      float zz = z[k][j] + rb[k];
      sz += zz;
      sz2 += zz * zz;
    }
    vals[k] = sz;
    vals[3 + k] = sz2;
  }

  __shared__ float redsh[4][6];
  const int wave = t >> 6, lane = t & 63;
#pragma unroll
  for (int v = 0; v < 6; v++) {
    float val = vals[v];
#pragma unroll
    for (int off = 32; off; off >>= 1) val += __shfl_down(val, off, 64);
    if (lane == 0) redsh[wave][v] = val;
  }
  __syncthreads();
  if (t < 6)
    partials[blk * 6 + t] = redsh[0][t] + redsh[1][t] + redsh[2][t] + redsh[3][t];
}

// ---------------------------------------------------------------------------
// Kernel 2: fold partials -> BN stats -> per-batch angle -> cos_theta[8]
// ---------------------------------------------------------------------------
__global__ __launch_bounds__(256) void k_stats(const float* __restrict__ partials,
                                               const float* __restrict__ bn_gamma,
                                               const float* __restrict__ bn_beta,
                                               float* __restrict__ cos_theta) {
  __shared__ float Msh[8][3];     // per-batch z sums
  __shared__ float varsum[3];     // global z^2 sums
  const int t = threadIdx.x;

  if (t < 24) {
    int b = t / 3, c = t - b * 3;
    float s = 0.f;
    for (int i = 0; i < 256; i++) s += partials[(b * 256 + i) * 6 + c];
    Msh[b][c] = s;
  }
  if (t >= 64) {  // 3 waves: c = 0..2
    int c = (t - 64) >> 6;
    int lane = t & 63;
    float s = 0.f;
    for (int i = lane; i < 2048; i += 64) s += partials[i * 6 + 3 + c];
#pragma unroll
    for (int off = 32; off; off >>= 1) s += __shfl_down(s, off, 64);
    if (lane == 0) varsum[c] = s;
  }
  __syncthreads();

  if (t < 8) {
    const float invN = 1.0f / (8.0f * 262144.0f);
    const float invHW = 1.0f / 262144.0f;
    float angle = 0.f;
#pragma unroll
    for (int c = 0; c < 3; c++) {
      float tot = 0.f;
#pragma unroll
      for (int b = 0; b < 8; b++) tot += Msh[b][c];
      float mu = tot * invN;
      float var = varsum[c] * invN - mu * mu;
      float rs = rsqrtf(var + 1e-5f);
      angle += (Msh[t][c] * invHW - mu) * rs * bn_gamma[c] + bn_beta[c];
    }
    float a = tanhf(angle) * 0.7853981633974483f;  // pi/4
    cos_theta[t] = cosf(a);
  }
}

// ---------------------------------------------------------------------------
// Kernel 3: phase-rotate FFT weights + factorized 3x3x3 inverse DFT, mid slice.
// w2d[b][c][p*3+q][o] = Re{ (1/27) sum_{k1,k2,k3} W[o,c,k1,k2,k3]
//                            * u_{k1} u_{k2} u_{k3} * w^{k1*1 + k2*p + k3*q} }
// with u_k = exp(-2*pi*i*cos_theta*f_k), f = [0, 1/3, -1/3], w = exp(2*pi*i/3)
// ---------------------------------------------------------------------------
__global__ __launch_bounds__(256) void k_rotw(const float* __restrict__ wfr,
                                              const float* __restrict__ wfi,
                                              const float* __restrict__ cos_theta,
                                              float* __restrict__ w2d) {
  const int b = blockIdx.x;
  const int t = threadIdx.x;
  const int o = t & 15;
  const int c = t >> 4;

  const float ct = cos_theta[b];
  const float phi = ct * 2.0943951023931953f;  // 2*pi/3 * ct
  float sp, cp;
  sincosf(phi, &sp, &cp);
  const float ur[3] = {1.f, cp, cp};
  const float ui[3] = {0.f, -sp, sp};
  const float wr3[3] = {1.f, -0.5f, -0.5f};
  const float wi3[3] = {0.f, 0.8660254037844386f, -0.8660254037844386f};

  float cr[3][3], ci[3][3];  // coef[k][m] = u_k * w^{(k*m)%3}
#pragma unroll
  for (int k = 0; k < 3; k++)
#pragma unroll
    for (int m = 0; m < 3; m++) {
      int e = (k * m) % 3;
      cr[k][m] = ur[k] * wr3[e] - ui[k] * wi3[e];
      ci[k][m] = ur[k] * wi3[e] + ui[k] * wr3[e];
    }

  const float* Ar = wfr + (o * 16 + c) * 27;
  const float* Ai = wfi + (o * 16 + c) * 27;
  float ar[27], ai[27];
#pragma unroll
  for (int i = 0; i < 27; i++) {
    ar[i] = Ar[i];
    ai[i] = Ai[i];
  }

  float g1r[27], g1i[27];  // [k1][k2][q]
#pragma unroll
  for (int k1 = 0; k1 < 3; k1++)
#pragma unroll
    for (int k2 = 0; k2 < 3; k2++)
#pragma unroll
      for (int q = 0; q < 3; q++) {
        float sr = 0.f, si = 0.f;
#pragma unroll
        for (int k3 = 0; k3 < 3; k3++) {
          float xr = ar[(k1 * 3 + k2) * 3 + k3];
          float xi = ai[(k1 * 3 + k2) * 3 + k3];
          sr += xr * cr[k3][q] - xi * ci[k3][q];
          si += xr * ci[k3][q] + xi * cr[k3][q];
        }
        g1r[(k1 * 3 + k2) * 3 + q] = sr;
        g1i[(k1 * 3 + k2) * 3 + q] = si;
      }

  float g2r[27], g2i[27];  // [k1][p][q]
#pragma unroll
  for (int k1 = 0; k1 < 3; k1++)
#pragma unroll
    for (int p = 0; p < 3; p++)
#pragma unroll
      for (int q = 0; q < 3; q++) {
        float sr = 0.f, si = 0.f;
#pragma unroll
        for (int k2 = 0; k2 < 3; k2++) {
          float xr = g1r[(k1 * 3 + k2) * 3 + q];
          float xi = g1i[(k1 * 3 + k2) * 3 + q];
          sr += xr * cr[k2][p] - xi * ci[k2][p];
          si += xr * ci[k2][p] + xi * cr[k2][p];
        }
        g2r[(k1 * 3 + p) * 3 + q] = sr;
        g2i[(k1 * 3 + p) * 3 + q] = si;
      }

#pragma unroll
  for (int p = 0; p < 3; p++)
#pragma unroll
    for (int q = 0; q < 3; q++) {
      float s = 0.f;
#pragma unroll
      for (int k1 = 0; k1 < 3; k1++) {
        // d_{k1} = coef[k1][1]  (mid slice index 1 on the first ifft axis)
        s += g2r[(k1 * 3 + p) * 3 + q] * cr[k1][1] -
             g2i[(k1 * 3 + p) * 3 + q] * ci[k1][1];
      }
      w2d[((b * 16 + c) * 9 + (p * 3 + q)) * 16 + o] = s * (1.0f / 27.0f);
    }
}

// ---------------------------------------------------------------------------
// Kernel 4: per-batch 16->16 channel 3x3 conv, pad 1, stride 1.
// Tile: 32 (cols) x 16 (rows), all 16 output channels.
// Thread map: row = t&15, og = (t>>4)&3 (4 o each), cg = t>>6 (8 cols each).
//  -> LDS x reads: lanes vary row (stride 36 words, 2-way alias = free) and
//     og (same addr, broadcast). Weight reads: 4 distinct float4 (banks 0-15),
//     conflict-free.
// ---------------------------------------------------------------------------
__global__ __launch_bounds__(256) void k_conv(const float* __restrict__ x,
                                              const float* __restrict__ w2d,
                                              float* __restrict__ out) {
  __shared__ __align__(16) float xs[16][18][36];   // [c][row][col], padded
  __shared__ __align__(16) float wsh[16][9][16];   // [c][tap][o]

  const int b = blockIdx.z;
  const int col0 = blockIdx.x * 32;
  const int row0 = blockIdx.y * 16;
  const int t = threadIdx.x;

  // weights: direct linear copy (ws already in [c][tap][o] order per batch)
  const float* wsrc = w2d + b * 2304;
  for (int i = t; i < 2304; i += 256) ((float*)wsh)[i] = wsrc[i];

  // x tile with halo: rows row0-1..row0+16, cols col0-1..col0+32
  const float* xb = x + (size_t)b * CIN * HW;
  for (int i = t; i < 16 * 18 * 34; i += 256) {
    int c = i / 612;            // 18*34
    int rem = i - c * 612;
    int r = rem / 34;
    int col = rem - r * 34;
    int gr = row0 - 1 + r;
    int gc = col0 - 1 + col;
    float v = 0.f;
    if ((unsigned)gr < 512u && (unsigned)gc < 512u)
      v = xb[c * HW + gr * 512 + gc];
    xs[c][r][col] = v;
  }
  __syncthreads();

  const int row = t & 15;
  const int og = (t >> 4) & 3;
  const int cg = t >> 6;
  const int cb = cg * 8;

  float acc[4][8];
#pragma unroll
  for (int o = 0; o < 4; o++)
#pragma unroll
    for (int k = 0; k < 8; k++) acc[o][k] = 0.f;

  for (int c = 0; c < 16; c++) {
    float4 wv[9];
#pragma unroll
    for (int tap = 0; tap < 9; tap++)
      wv[tap] = *reinterpret_cast<const float4*>(&wsh[c][tap][og * 4]);

#pragma unroll
    for (int dr = 0; dr < 3; dr++) {
      const float* base = &xs[c][row + dr][cb];
      float4 a = *reinterpret_cast<const float4*>(base);
      float4 bb = *reinterpret_cast<const float4*>(base + 4);
      float2 cc = *reinterpret_cast<const float2*>(base + 8);
      float xr[10] = {a.x, a.y, a.z, a.w, bb.x, bb.y, bb.z, bb.w, cc.x, cc.y};
#pragma unroll
      for (int dx = 0; dx < 3; dx++) {
        float4 w4 = wv[dr * 3 + dx];
#pragma unroll
        for (int k = 0; k < 8; k++) {
          float xv = xr[k + dx];
          acc[0][k] += w4.x * xv;
          acc[1][k] += w4.y * xv;
          acc[2][k] += w4.z * xv;
          acc[3][k] += w4.w * xv;
        }
      }
    }
  }

  float* ob = out + ((size_t)b * OUTC + og * 4) * HW + (row0 + row) * 512 + col0 + cb;
#pragma unroll
  for (int o = 0; o < 4; o++) {
    float* dst = ob + (size_t)o * HW;
    *reinterpret_cast<float4*>(dst) =
        make_float4(acc[o][0], acc[o][1], acc[o][2], acc[o][3]);
    *reinterpret_cast<float4*>(dst + 4) =
        make_float4(acc[o][4], acc[o][5], acc[o][6], acc[o][7]);
  }
}

extern "C" void kernel_launch(void* const* d_in, const int* in_sizes, int n_in,
                              void* d_out, int out_size, void* d_ws, size_t ws_size,
                              hipStream_t stream) {
  const float* x      = (const float*)d_in[0];
  const float* wfr    = (const float*)d_in[1];
  const float* wfi    = (const float*)d_in[2];
  const float* rot_w  = (const float*)d_in[3];
  const float* rot_b  = (const float*)d_in[4];
  const float* bn_g   = (const float*)d_in[5];
  const float* bn_b   = (const float*)d_in[6];
  float* out = (float*)d_out;
  float* ws  = (float*)d_ws;

  float* partials = ws + WS_PARTIALS;
  float* cosw     = ws + WS_COS;
  float* w2d      = ws + WS_W2D;

  k_reduce<<<2048, 256, 0, stream>>>(x, rot_w, rot_b, partials);
  k_stats<<<1, 256, 0, stream>>>(partials, bn_g, bn_b, cosw);
  k_rotw<<<8, 256, 0, stream>>>(wfr, wfi, cosw, w2d);
  dim3 grid(16, 32, 8);
  k_conv<<<grid, 256, 0, stream>>>(x, w2d, out);
}

// Round 3
// 318.211 us; speedup vs baseline: 1.3665x; 1.3665x over previous
//
#include <hip/hip_runtime.h>

#define HW 262144           // 512*512
#define CIN 16
#define OUTC 16

// ws layout (float offsets)
#define WS_PARTIALS 0       // [2048][6] floats
#define WS_COS      12288   // [8] floats
#define WS_WB_F     12296   // ushort region: [8][5 kb][2 hl][64 lane][8 j] bf16 = 40960 u16

typedef float  floatx4 __attribute__((ext_vector_type(4)));
typedef short  bf16x8  __attribute__((ext_vector_type(8)));

__device__ __forceinline__ ushort bf16_rne(float f) {
  unsigned u = __float_as_uint(f);
  unsigned r = (u + 0x7FFFu + ((u >> 16) & 1u)) >> 16;
  return (ushort)r;
}
__device__ __forceinline__ void bf16_split(float f, ushort& hi, ushort& lo) {
  hi = bf16_rne(f);
  float fh = __uint_as_float(((unsigned)hi) << 16);
  lo = bf16_rne(f - fh);
}

// ---------------------------------------------------------------------------
// Kernel 1: streaming reduction over x.
// z_c = sum_k rot_w[c,k]*x[b,k,p] + rot_b[c]  (c = 0..2)
// per block (fixed batch b): partial sums of z_c and z_c^2.
// ---------------------------------------------------------------------------
__global__ __launch_bounds__(256) void k_reduce(const float* __restrict__ x,
                                                const float* __restrict__ rot_w,
                                                const float* __restrict__ rot_b,
                                                float* __restrict__ partials) {
  const int blk = blockIdx.x;       // 0..2047
  const int b = blk >> 8;
  const int s = blk & 255;
  const int t = threadIdx.x;

  float rw[3][16];
#pragma unroll
  for (int k = 0; k < 3; k++)
#pragma unroll
    for (int c = 0; c < 16; c++) rw[k][c] = rot_w[k * 16 + c];
  float rb[3];
#pragma unroll
  for (int k = 0; k < 3; k++) rb[k] = rot_b[k];

  const float* xb = x + (size_t)b * CIN * HW + s * 1024 + t * 4;

  float z[3][4];
#pragma unroll
  for (int k = 0; k < 3; k++)
#pragma unroll
    for (int j = 0; j < 4; j++) z[k][j] = 0.f;

#pragma unroll
  for (int c = 0; c < 16; c++) {
    float4 v = *reinterpret_cast<const float4*>(xb + (size_t)c * HW);
#pragma unroll
    for (int k = 0; k < 3; k++) {
      z[k][0] += rw[k][c] * v.x;
      z[k][1] += rw[k][c] * v.y;
      z[k][2] += rw[k][c] * v.z;
      z[k][3] += rw[k][c] * v.w;
    }
  }

  float vals[6];
#pragma unroll
  for (int k = 0; k < 3; k++) {
    float sz = 0.f, sz2 = 0.f;
#pragma unroll
    for (int j = 0; j < 4; j++) {
      float zz = z[k][j] + rb[k];
      sz += zz;
      sz2 += zz * zz;
    }
    vals[k] = sz;
    vals[3 + k] = sz2;
  }

  __shared__ float redsh[4][6];
  const int wave = t >> 6, lane = t & 63;
#pragma unroll
  for (int v = 0; v < 6; v++) {
    float val = vals[v];
#pragma unroll
    for (int off = 32; off; off >>= 1) val += __shfl_down(val, off, 64);
    if (lane == 0) redsh[wave][v] = val;
  }
  __syncthreads();
  if (t < 6)
    partials[blk * 6 + t] = redsh[0][t] + redsh[1][t] + redsh[2][t] + redsh[3][t];
}

// ---------------------------------------------------------------------------
// Kernel 2: fold partials -> BN stats -> per-batch angle -> cos_theta[8]
// ---------------------------------------------------------------------------
__global__ __launch_bounds__(256) void k_stats(const float* __restrict__ partials,
                                               const float* __restrict__ bn_gamma,
                                               const float* __restrict__ bn_beta,
                                               float* __restrict__ cos_theta) {
  __shared__ float Msh[8][3];
  __shared__ float varsum[3];
  const int t = threadIdx.x;

  if (t < 24) {
    int b = t / 3, c = t - b * 3;
    float s = 0.f;
    for (int i = 0; i < 256; i++) s += partials[(b * 256 + i) * 6 + c];
    Msh[b][c] = s;
  }
  if (t >= 64) {
    int c = (t - 64) >> 6;
    int lane = t & 63;
    float s = 0.f;
    for (int i = lane; i < 2048; i += 64) s += partials[i * 6 + 3 + c];
#pragma unroll
    for (int off = 32; off; off >>= 1) s += __shfl_down(s, off, 64);
    if (lane == 0) varsum[c] = s;
  }
  __syncthreads();

  if (t < 8) {
    const float invN = 1.0f / (8.0f * 262144.0f);
    const float invHW = 1.0f / 262144.0f;
    float angle = 0.f;
#pragma unroll
    for (int c = 0; c < 3; c++) {
      float tot = 0.f;
#pragma unroll
      for (int b = 0; b < 8; b++) tot += Msh[b][c];
      float mu = tot * invN;
      float var = varsum[c] * invN - mu * mu;
      float rs = rsqrtf(var + 1e-5f);
      angle += (Msh[t][c] * invHW - mu) * rs * bn_gamma[c] + bn_beta[c];
    }
    float a = tanhf(angle) * 0.7853981633974483f;
    cos_theta[t] = cosf(a);
  }
}

// ---------------------------------------------------------------------------
// Kernel 3: phase-rotate + factorized 3-pt inverse DFT (mid slice), streaming,
// emitting bf16 hi/lo weights directly in the per-lane MFMA B-fragment layout:
// wB[b][kb][hl][lane][j], k = tap*16 + c, kb = k>>5,
// lane = ((k>>3)&3)*16 + o, j = k&7. k in [144,160) zero-padded.
// ---------------------------------------------------------------------------
__global__ __launch_bounds__(256) void k_rotw(const float* __restrict__ wfr,
                                              const float* __restrict__ wfi,
                                              const float* __restrict__ cos_theta,
                                              ushort* __restrict__ wB) {
  const int b = blockIdx.x;
  const int t = threadIdx.x;
  const int o = t & 15;
  const int c = t >> 4;

  const float ct = cos_theta[b];
  const float phi = ct * 2.0943951023931953f;  // 2*pi/3 * ct
  float sp, cp;
  sincosf(phi, &sp, &cp);
  const float ur[3] = {1.f, cp, cp};
  const float ui[3] = {0.f, -sp, sp};
  const float wr3[3] = {1.f, -0.5f, -0.5f};
  const float wi3[3] = {0.f, 0.8660254037844386f, -0.8660254037844386f};

  float cr[3][3], ci[3][3];
#pragma unroll
  for (int k = 0; k < 3; k++)
#pragma unroll
    for (int m = 0; m < 3; m++) {
      int e = (k * m) % 3;
      cr[k][m] = ur[k] * wr3[e] - ui[k] * wi3[e];
      ci[k][m] = ur[k] * wi3[e] + ui[k] * wr3[e];
    }

  const float* Ar = wfr + (o * 16 + c) * 27;
  const float* Ai = wfi + (o * 16 + c) * 27;

  float outv[9];
#pragma unroll
  for (int i = 0; i < 9; i++) outv[i] = 0.f;

#pragma unroll
  for (int k1 = 0; k1 < 3; k1++) {
    float ar[9], ai[9];
#pragma unroll
    for (int i = 0; i < 9; i++) { ar[i] = Ar[k1 * 9 + i]; ai[i] = Ai[k1 * 9 + i]; }
    float hr[3][3], hi2[3][3];
#pragma unroll
    for (int k2 = 0; k2 < 3; k2++)
#pragma unroll
      for (int q = 0; q < 3; q++) {
        float sr = 0.f, si = 0.f;
#pragma unroll
        for (int k3 = 0; k3 < 3; k3++) {
          float xr = ar[k2 * 3 + k3], xi = ai[k2 * 3 + k3];
          sr += xr * cr[k3][q] - xi * ci[k3][q];
          si += xr * ci[k3][q] + xi * cr[k3][q];
        }
        hr[k2][q] = sr;
        hi2[k2][q] = si;
      }
    float drr = cr[k1][1], dii = ci[k1][1];
#pragma unroll
    for (int p = 0; p < 3; p++)
#pragma unroll
      for (int q = 0; q < 3; q++) {
        float sr = 0.f, si = 0.f;
#pragma unroll
        for (int k2 = 0; k2 < 3; k2++) {
          sr += hr[k2][q] * cr[k2][p] - hi2[k2][q] * ci[k2][p];
          si += hr[k2][q] * ci[k2][p] + hi2[k2][q] * cr[k2][p];
        }
        outv[p * 3 + q] += sr * drr - si * dii;
      }
  }

#pragma unroll
  for (int tap = 0; tap < 9; tap++) {
    float v = outv[tap] * (1.0f / 27.0f);
    int k = tap * 16 + c;
    int kb = k >> 5;
    int g = (k >> 3) & 3;
    int j = k & 7;
    int ln = g * 16 + o;
    ushort hi, lo;
    bf16_split(v, hi, lo);
    int idx = ((b * 5 + kb) * 2) * 512 + ln * 8 + j;
    wB[idx] = hi;         // hl = 0
    wB[idx + 512] = lo;   // hl = 1
  }

  // zero-pad k in [144,160), both hl: 512 entries, 2 per thread
#pragma unroll
  for (int u = 0; u < 2; u++) {
    int e = t * 2 + u;
    int hl = e >> 8;
    int rem = e & 255;
    int kk = 144 + (rem >> 4);
    int o2 = rem & 15;
    int g2 = (kk >> 3) & 3;
    int ln2 = g2 * 16 + o2;
    int j2 = kk & 7;
    wB[((b * 5 + 4) * 2 + hl) * 512 + ln2 * 8 + j2] = 0;
  }
}

// ---------------------------------------------------------------------------
// Kernel 4: implicit-GEMM conv via mfma_f32_16x16x32_bf16, bf16x3 split.
// Block: 16 rows x 32 cols x 16 o, one batch. 4 waves, each wave 8 tiles of
// (16 positions x 16 o).
// LDS x-tile: [18 rows][34 cols][4 chunks of 16B], chunk = (hl*2 + c>>3) ^
// ((col>>1)&3); row stride 1096 u16 = 2192 B. A-fragment = one ds_read_b128
// per lane. K = 9 taps*16c = 144, padded to 160 (5 kb of 32).
// ---------------------------------------------------------------------------
__global__ __launch_bounds__(256, 4) void k_conv(const float* __restrict__ x,
                                                 const ushort* __restrict__ wB,
                                                 float* __restrict__ out) {
  __shared__ ushort xsb[18 * 1096];   // 39456 B

  const int b = blockIdx.z;
  const int col0 = blockIdx.x * 32;
  const int row0 = blockIdx.y * 16;
  const int t = threadIdx.x;
  const int lane = t & 63;

  // --- weight B-fragments (L2-resident, per-lane layout) ---
  const ushort* wBb = wB + b * 5120;
  bf16x8 wh[5], wl[5];
#pragma unroll
  for (int kb = 0; kb < 5; kb++) {
    wh[kb] = *reinterpret_cast<const bf16x8*>(wBb + (kb * 2 + 0) * 512 + lane * 8);
    wl[kb] = *reinterpret_cast<const bf16x8*>(wBb + (kb * 2 + 1) * 512 + lane * 8);
  }

  // --- stage x tile (fp32 -> bf16 hi/lo, swizzled) ---
  const float* xb = x + (size_t)b * CIN * HW;
  // interior cols (image cols col0..col0+31 -> xs cols 1..32), aligned float4
  for (int i = t; i < 2304; i += 256) {     // 16c * 18r * 8grp
    int c = i / 144;
    int rem = i - c * 144;
    int r = rem >> 3;
    int grp = rem & 7;
    int gr = row0 - 1 + r;
    int gc = col0 + grp * 4;
    float4 v = make_float4(0.f, 0.f, 0.f, 0.f);
    if ((unsigned)gr < 512u)
      v = *reinterpret_cast<const float4*>(xb + (size_t)c * HW + gr * 512 + gc);
    float vv[4] = {v.x, v.y, v.z, v.w};
    int colb = grp * 4 + 1;
#pragma unroll
    for (int j = 0; j < 4; j++) {
      ushort hi, lo;
      bf16_split(vv[j], hi, lo);
      int col = colb + j;
      int base = r * 1096 + col * 32;
      int swz = (col >> 1) & 3;
      int ch = (c >> 3) ^ swz;
      xsb[base + ch * 8 + (c & 7)] = hi;
      xsb[base + (ch ^ 2) * 8 + (c & 7)] = lo;
    }
  }
  // halo cols (xs col 0 = image col0-1, xs col 33 = image col0+32)
  for (int i = t; i < 576; i += 256) {      // 16c * 18r * 2
    int c = i / 36;
    int rem = i - c * 36;
    int r = rem >> 1;
    int side = rem & 1;
    int col = side ? 33 : 0;
    int gr = row0 - 1 + r;
    int gc = col0 - 1 + side * 33;
    float v = 0.f;
    if ((unsigned)gr < 512u && (unsigned)gc < 512u)
      v = xb[(size_t)c * HW + gr * 512 + gc];
    ushort hi, lo;
    bf16_split(v, hi, lo);
    int base = r * 1096 + col * 32;
    int swz = (col >> 1) & 3;
    int ch = (c >> 3) ^ swz;
    xsb[base + ch * 8 + (c & 7)] = hi;
    xsb[base + (ch ^ 2) * 8 + (c & 7)] = lo;
  }

  // --- per-lane A-fragment offsets (tile-independent) ---
  const int m = lane & 15;
  const int g = lane >> 4;
  const int chalf = g & 1;
  const int tsel = g >> 1;
  int offh[5], offl[5];
#pragma unroll
  for (int kb = 0; kb < 5; kb++) {
    int tap = kb * 2 + tsel;
    if (tap > 8) tap = 8;        // pad reads real addrs; weights are zero
    int dy = tap / 3;
    int dx = tap - dy * 3;
    int mdx = m + dx;
    int swz = (mdx >> 1) & 3;    // (col>>1)&3 with col = cg*16 + mdx (cg*16 ≡ 0 mod 8)
    offh[kb] = dy * 1096 + mdx * 32 + ((chalf ^ swz) << 3);
    offl[kb] = dy * 1096 + mdx * 32 + (((2 | chalf) ^ swz) << 3);
  }

  __syncthreads();

  // --- main: 8 tiles per wave, 15 MFMA each ---
  const int w = t >> 6;
  const int oo = lane & 15;
  const int quad = lane >> 4;
#pragma unroll
  for (int s = 0; s < 8; s++) {
    int r = w * 4 + (s >> 1);
    int cg = s & 1;
    int base = r * 1096 + cg * 512;
    floatx4 acc = {0.f, 0.f, 0.f, 0.f};
#pragma unroll
    for (int kb = 0; kb < 5; kb++) {
      bf16x8 a_hi = *reinterpret_cast<const bf16x8*>(&xsb[base + offh[kb]]);
      bf16x8 a_lo = *reinterpret_cast<const bf16x8*>(&xsb[base + offl[kb]]);
      acc = __builtin_amdgcn_mfma_f32_16x16x32_bf16(a_hi, wh[kb], acc, 0, 0, 0);
      acc = __builtin_amdgcn_mfma_f32_16x16x32_bf16(a_hi, wl[kb], acc, 0, 0, 0);
      acc = __builtin_amdgcn_mfma_f32_16x16x32_bf16(a_lo, wh[kb], acc, 0, 0, 0);
    }
    // C/D: n(o) = lane&15, m(pos) = (lane>>4)*4 + reg
    float* dst = out + (size_t)(b * OUTC + oo) * HW + (size_t)(row0 + r) * 512 +
                 col0 + cg * 16 + quad * 4;
    *reinterpret_cast<float4*>(dst) = make_float4(acc[0], acc[1], acc[2], acc[3]);
  }
}

extern "C" void kernel_launch(void* const* d_in, const int* in_sizes, int n_in,
                              void* d_out, int out_size, void* d_ws, size_t ws_size,
                              hipStream_t stream) {
  const float* x      = (const float*)d_in[0];
  const float* wfr    = (const float*)d_in[1];
  const float* wfi    = (const float*)d_in[2];
  const float* rot_w  = (const float*)d_in[3];
  const float* rot_b  = (const float*)d_in[4];
  const float* bn_g   = (const float*)d_in[5];
  const float* bn_b   = (const float*)d_in[6];
  float* out = (float*)d_out;
  float* ws  = (float*)d_ws;

  float* partials = ws + WS_PARTIALS;
  float* cosw     = ws + WS_COS;
  ushort* wB      = (ushort*)(ws + WS_WB_F);

  k_reduce<<<2048, 256, 0, stream>>>(x, rot_w, rot_b, partials);
  k_stats<<<1, 256, 0, stream>>>(partials, bn_g, bn_b, cosw);
  k_rotw<<<8, 256, 0, stream>>>(wfr, wfi, cosw, wB);
  dim3 grid(16, 32, 8);
  k_conv<<<grid, 256, 0, stream>>>(x, wB, out);
}

// Round 6
// 296.176 us; speedup vs baseline: 1.4682x; 1.0744x over previous
//
#include <hip/hip_runtime.h>

#define HW 262144           // 512*512
#define CIN 16
#define OUTC 16

// ws layout (float offsets)
#define WS_PARTIALS 0       // [2048][6] floats
#define WS_COS      12288   // [8] floats
#define WS_WB_F     12296   // ushort region: [8][5 kb][2 hl][64 lane][8 j] bf16 = 40960 u16

typedef float  floatx4 __attribute__((ext_vector_type(4)));
typedef short  bf16x8  __attribute__((ext_vector_type(8)));

__device__ __forceinline__ ushort bf16_rne(float f) {
  unsigned u = __float_as_uint(f);
  unsigned r = (u + 0x7FFFu + ((u >> 16) & 1u)) >> 16;
  return (ushort)r;
}
__device__ __forceinline__ void bf16_split(float f, ushort& hi, ushort& lo) {
  hi = bf16_rne(f);
  float fh = __uint_as_float(((unsigned)hi) << 16);
  lo = bf16_rne(f - fh);
}

// ---------------------------------------------------------------------------
// Kernel 1: streaming reduction over x.
// ---------------------------------------------------------------------------
__global__ __launch_bounds__(256) void k_reduce(const float* __restrict__ x,
                                                const float* __restrict__ rot_w,
                                                const float* __restrict__ rot_b,
                                                float* __restrict__ partials) {
  const int blk = blockIdx.x;       // 0..2047
  const int b = blk >> 8;
  const int s = blk & 255;
  const int t = threadIdx.x;

  float rw[3][16];
#pragma unroll
  for (int k = 0; k < 3; k++)
#pragma unroll
    for (int c = 0; c < 16; c++) rw[k][c] = rot_w[k * 16 + c];
  float rb[3];
#pragma unroll
  for (int k = 0; k < 3; k++) rb[k] = rot_b[k];

  const float* xb = x + (size_t)b * CIN * HW + s * 1024 + t * 4;

  float z[3][4];
#pragma unroll
  for (int k = 0; k < 3; k++)
#pragma unroll
    for (int j = 0; j < 4; j++) z[k][j] = 0.f;

#pragma unroll
  for (int c = 0; c < 16; c++) {
    float4 v = *reinterpret_cast<const float4*>(xb + (size_t)c * HW);
#pragma unroll
    for (int k = 0; k < 3; k++) {
      z[k][0] += rw[k][c] * v.x;
      z[k][1] += rw[k][c] * v.y;
      z[k][2] += rw[k][c] * v.z;
      z[k][3] += rw[k][c] * v.w;
    }
  }

  float vals[6];
#pragma unroll
  for (int k = 0; k < 3; k++) {
    float sz = 0.f, sz2 = 0.f;
#pragma unroll
    for (int j = 0; j < 4; j++) {
      float zz = z[k][j] + rb[k];
      sz += zz;
      sz2 += zz * zz;
    }
    vals[k] = sz;
    vals[3 + k] = sz2;
  }

  __shared__ float redsh[4][6];
  const int wave = t >> 6, lane = t & 63;
#pragma unroll
  for (int v = 0; v < 6; v++) {
    float val = vals[v];
#pragma unroll
    for (int off = 32; off; off >>= 1) val += __shfl_down(val, off, 64);
    if (lane == 0) redsh[wave][v] = val;
  }
  __syncthreads();
  if (t < 6)
    partials[blk * 6 + t] = redsh[0][t] + redsh[1][t] + redsh[2][t] + redsh[3][t];
}

// ---------------------------------------------------------------------------
// Kernel 2: fold partials -> BN stats -> per-batch angle -> cos_theta[8]
// ---------------------------------------------------------------------------
__global__ __launch_bounds__(256) void k_stats(const float* __restrict__ partials,
                                               const float* __restrict__ bn_gamma,
                                               const float* __restrict__ bn_beta,
                                               float* __restrict__ cos_theta) {
  __shared__ float Msh[8][3];
  __shared__ float varsum[3];
  const int t = threadIdx.x;

  if (t < 24) {
    int b = t / 3, c = t - b * 3;
    float s = 0.f;
    for (int i = 0; i < 256; i++) s += partials[(b * 256 + i) * 6 + c];
    Msh[b][c] = s;
  }
  if (t >= 64) {
    int c = (t - 64) >> 6;
    int lane = t & 63;
    float s = 0.f;
    for (int i = lane; i < 2048; i += 64) s += partials[i * 6 + 3 + c];
#pragma unroll
    for (int off = 32; off; off >>= 1) s += __shfl_down(s, off, 64);
    if (lane == 0) varsum[c] = s;
  }
  __syncthreads();

  if (t < 8) {
    const float invN = 1.0f / (8.0f * 262144.0f);
    const float invHW = 1.0f / 262144.0f;
    float angle = 0.f;
#pragma unroll
    for (int c = 0; c < 3; c++) {
      float tot = 0.f;
#pragma unroll
      for (int b = 0; b < 8; b++) tot += Msh[b][c];
      float mu = tot * invN;
      float var = varsum[c] * invN - mu * mu;
      float rs = rsqrtf(var + 1e-5f);
      angle += (Msh[t][c] * invHW - mu) * rs * bn_gamma[c] + bn_beta[c];
    }
    float a = tanhf(angle) * 0.7853981633974483f;
    cos_theta[t] = cosf(a);
  }
}

// ---------------------------------------------------------------------------
// Kernel 3: phase-rotate + factorized 3-pt inverse DFT (mid slice), streaming,
// emitting bf16 hi/lo weights in the per-lane MFMA B-fragment layout.
// ---------------------------------------------------------------------------
__global__ __launch_bounds__(256) void k_rotw(const float* __restrict__ wfr,
                                              const float* __restrict__ wfi,
                                              const float* __restrict__ cos_theta,
                                              ushort* __restrict__ wB) {
  const int b = blockIdx.x;
  const int t = threadIdx.x;
  const int o = t & 15;
  const int c = t >> 4;

  const float ct = cos_theta[b];
  const float phi = ct * 2.0943951023931953f;  // 2*pi/3 * ct
  float sp, cp;
  sincosf(phi, &sp, &cp);
  const float ur[3] = {1.f, cp, cp};
  const float ui[3] = {0.f, -sp, sp};
  const float wr3[3] = {1.f, -0.5f, -0.5f};
  const float wi3[3] = {0.f, 0.8660254037844386f, -0.8660254037844386f};

  float cr[3][3], ci[3][3];
#pragma unroll
  for (int k = 0; k < 3; k++)
#pragma unroll
    for (int m = 0; m < 3; m++) {
      int e = (k * m) % 3;
      cr[k][m] = ur[k] * wr3[e] - ui[k] * wi3[e];
      ci[k][m] = ur[k] * wi3[e] + ui[k] * wr3[e];
    }

  const float* Ar = wfr + (o * 16 + c) * 27;
  const float* Ai = wfi + (o * 16 + c) * 27;

  float outv[9];
#pragma unroll
  for (int i = 0; i < 9; i++) outv[i] = 0.f;

#pragma unroll
  for (int k1 = 0; k1 < 3; k1++) {
    float ar[9], ai[9];
#pragma unroll
    for (int i = 0; i < 9; i++) { ar[i] = Ar[k1 * 9 + i]; ai[i] = Ai[k1 * 9 + i]; }
    float hr[3][3], hi2[3][3];
#pragma unroll
    for (int k2 = 0; k2 < 3; k2++)
#pragma unroll
      for (int q = 0; q < 3; q++) {
        float sr = 0.f, si = 0.f;
#pragma unroll
        for (int k3 = 0; k3 < 3; k3++) {
          float xr = ar[k2 * 3 + k3], xi = ai[k2 * 3 + k3];
          sr += xr * cr[k3][q] - xi * ci[k3][q];
          si += xr * ci[k3][q] + xi * cr[k3][q];
        }
        hr[k2][q] = sr;
        hi2[k2][q] = si;
      }
    float drr = cr[k1][1], dii = ci[k1][1];
#pragma unroll
    for (int p = 0; p < 3; p++)
#pragma unroll
      for (int q = 0; q < 3; q++) {
        float sr = 0.f, si = 0.f;
#pragma unroll
        for (int k2 = 0; k2 < 3; k2++) {
          sr += hr[k2][q] * cr[k2][p] - hi2[k2][q] * ci[k2][p];
          si += hr[k2][q] * ci[k2][p] + hi2[k2][q] * cr[k2][p];
        }
        outv[p * 3 + q] += sr * drr - si * dii;
      }
  }

#pragma unroll
  for (int tap = 0; tap < 9; tap++) {
    float v = outv[tap] * (1.0f / 27.0f);
    int k = tap * 16 + c;
    int kb = k >> 5;
    int g = (k >> 3) & 3;
    int j = k & 7;
    int ln = g * 16 + o;
    ushort hi, lo;
    bf16_split(v, hi, lo);
    int idx = ((b * 5 + kb) * 2) * 512 + ln * 8 + j;
    wB[idx] = hi;         // hl = 0
    wB[idx + 512] = lo;   // hl = 1
  }

  // zero-pad k in [144,160), both hl
#pragma unroll
  for (int u = 0; u < 2; u++) {
    int e = t * 2 + u;
    int hl = e >> 8;
    int rem = e & 255;
    int kk = 144 + (rem >> 4);
    int o2 = rem & 15;
    int g2 = (kk >> 3) & 3;
    int ln2 = g2 * 16 + o2;
    int j2 = kk & 7;
    wB[((b * 5 + 4) * 2 + hl) * 512 + ln2 * 8 + j2] = 0;
  }
}

// ---------------------------------------------------------------------------
// Kernel 4: implicit-GEMM conv via mfma_f32_16x16x32_bf16, bf16x3 split.
// R4 changes: (1) staging = register-transpose gather (8 scalar loads ->
// 2x ds_write_b128, <=2-way bank alias) replacing conflicted u16 scatter;
// (2) XCD-aware 1D grid swizzle: each XCD owns one batch's 512 tiles
// row-major -> halo lines + 5KB weight block stay in its L2.
// ---------------------------------------------------------------------------
__global__ __launch_bounds__(256, 4) void k_conv(const float* __restrict__ x,
                                                 const ushort* __restrict__ wB,
                                                 float* __restrict__ out) {
  __shared__ ushort xsb[18 * 1096];   // 39456 B

  const int id = blockIdx.x;
  const int nid = (id & 7) * 512 + (id >> 3);   // XCD swizzle (4096 % 8 == 0)
  const int b = nid >> 9;
  const int rem0 = nid & 511;
  const int row0 = (rem0 >> 4) * 16;
  const int col0 = (rem0 & 15) * 32;
  const int t = threadIdx.x;
  const int lane = t & 63;

  // --- weight B-fragments (L2-resident, per-lane layout) ---
  const ushort* wBb = wB + b * 5120;
  bf16x8 wh[5], wl[5];
#pragma unroll
  for (int kb = 0; kb < 5; kb++) {
    wh[kb] = *reinterpret_cast<const bf16x8*>(wBb + (kb * 2 + 0) * 512 + lane * 8);
    wl[kb] = *reinterpret_cast<const bf16x8*>(wBb + (kb * 2 + 1) * 512 + lane * 8);
  }

  // --- stage x tile: per-thread gather of 8 channels -> hi/lo b128 writes ---
  const float* xb = x + (size_t)b * CIN * HW;
#pragma unroll
  for (int it = 0; it < 5; it++) {
    int p = it * 256 + t;                 // pair index over 18r * 34c * 2chalf
    if (p < 1224) {
      int row = p / 68;
      int rem2 = p - row * 68;
      int col = rem2 >> 1;
      int chalf = rem2 & 1;
      int gr = row0 - 1 + row;
      int gc = col0 - 1 + col;
      bool ok = ((unsigned)gr < 512u) && ((unsigned)gc < 512u);
      const float* src = xb + (size_t)(chalf * 8) * HW + gr * 512 + gc;
      bf16x8 hv, lv;
#pragma unroll
      for (int j = 0; j < 8; j++) {
        float v = ok ? src[(size_t)j * HW] : 0.f;
        ushort hi, lo;
        bf16_split(v, hi, lo);
        hv[j] = (short)hi;
        lv[j] = (short)lo;
      }
      int swz = (col >> 1) & 3;
      int base = row * 1096 + col * 32;
      *reinterpret_cast<bf16x8*>(&xsb[base + ((chalf ^ swz) << 3)]) = hv;
      *reinterpret_cast<bf16x8*>(&xsb[base + (((2 | chalf) ^ swz) << 3)]) = lv;
    }
  }

  // --- per-lane A-fragment offsets (tile-independent) ---
  const int m = lane & 15;
  const int g = lane >> 4;
  const int chalf = g & 1;
  const int tsel = g >> 1;
  int offh[5], offl[5];
#pragma unroll
  for (int kb = 0; kb < 5; kb++) {
    int tap = kb * 2 + tsel;
    if (tap > 8) tap = 8;        // pad reads real addrs; weights are zero
    int dy = tap / 3;
    int dx = tap - dy * 3;
    int mdx = m + dx;
    int swz = (mdx >> 1) & 3;
    offh[kb] = dy * 1096 + mdx * 32 + ((chalf ^ swz) << 3);
    offl[kb] = dy * 1096 + mdx * 32 + (((2 | chalf) ^ swz) << 3);
  }

  __syncthreads();

  // --- main: 8 tiles per wave, 15 MFMA each ---
  const int w = t >> 6;
  const int oo = lane & 15;
  const int quad = lane >> 4;
#pragma unroll
  for (int s = 0; s < 8; s++) {
    int r = w * 4 + (s >> 1);
    int cg = s & 1;
    int base = r * 1096 + cg * 512;
    floatx4 acc = {0.f, 0.f, 0.f, 0.f};
#pragma unroll
    for (int kb = 0; kb < 5; kb++) {
      bf16x8 a_hi = *reinterpret_cast<const bf16x8*>(&xsb[base + offh[kb]]);
      bf16x8 a_lo = *reinterpret_cast<const bf16x8*>(&xsb[base + offl[kb]]);
      acc = __builtin_amdgcn_mfma_f32_16x16x32_bf16(a_hi, wh[kb], acc, 0, 0, 0);
      acc = __builtin_amdgcn_mfma_f32_16x16x32_bf16(a_hi, wl[kb], acc, 0, 0, 0);
      acc = __builtin_amdgcn_mfma_f32_16x16x32_bf16(a_lo, wh[kb], acc, 0, 0, 0);
    }
    // C/D: n(o) = lane&15, m(pos) = (lane>>4)*4 + reg
    float* dst = out + (size_t)(b * OUTC + oo) * HW + (size_t)(row0 + r) * 512 +
                 col0 + cg * 16 + quad * 4;
    *reinterpret_cast<float4*>(dst) = make_float4(acc[0], acc[1], acc[2], acc[3]);
  }
}

extern "C" void kernel_launch(void* const* d_in, const int* in_sizes, int n_in,
                              void* d_out, int out_size, void* d_ws, size_t ws_size,
                              hipStream_t stream) {
  const float* x      = (const float*)d_in[0];
  const float* wfr    = (const float*)d_in[1];
  const float* wfi    = (const float*)d_in[2];
  const float* rot_w  = (const float*)d_in[3];
  const float* rot_b  = (const float*)d_in[4];
  const float* bn_g   = (const float*)d_in[5];
  const float* bn_b   = (const float*)d_in[6];
  float* out = (float*)d_out;
  float* ws  = (float*)d_ws;

  float* partials = ws + WS_PARTIALS;
  float* cosw     = ws + WS_COS;
  ushort* wB      = (ushort*)(ws + WS_WB_F);

  k_reduce<<<2048, 256, 0, stream>>>(x, rot_w, rot_b, partials);
  k_stats<<<1, 256, 0, stream>>>(partials, bn_g, bn_b, cosw);
  k_rotw<<<8, 256, 0, stream>>>(wfr, wfi, cosw, wB);
  k_conv<<<4096, 256, 0, stream>>>(x, wB, out);
}